// Round 14
// baseline (237.163 us; speedup 1.0000x reference)
//
#include <hip/hip_runtime.h>

#define NEG_SLOPE 0.2f
#define CH 2048      // edges per partition block (keeps LDS union at 32 KB)
#define DCAP 2048    // max edges per bucket handled via LDS fast path

__device__ inline unsigned short f2bf(float f) {
    unsigned u = __float_as_uint(f);
    unsigned r = (u + 0x7FFFu + ((u >> 16) & 1u)) >> 16;
    return (unsigned short)r;
}
__device__ inline unsigned pack2bf(float a, float b) {
    return (unsigned)f2bf(a) | ((unsigned)f2bf(b) << 16);
}
__device__ inline float bf2f(unsigned short s) {
    return __uint_as_float(((unsigned)s) << 16);
}
__device__ inline float bf2f_lo(unsigned u) { return __uint_as_float(u << 16); }
__device__ inline float bf2f_hi(unsigned u) { return __uint_as_float(u & 0xFFFF0000u); }
__device__ inline void wave_lds_fence() {
    asm volatile("s_waitcnt lgkmcnt(0)" ::: "memory");
}

// ===========================================================================
// FUSED: bucketAB (global histogram + scan, last-finisher) + bucketC (edge
// partition) || gemm1 (feat1b = h@W1 + el1/er1).
// Packed edge: (bucket<<22) | ((dst&63)<<16) | src   (requires N <= 65536)
// bucket_cnt layout: [0,NB) counts, [NB] ticket, [NB+1] scan-done flag.
// LDS union is exactly 32 KB -> 5 blocks/CU.
// ===========================================================================
__global__ __launch_bounds__(256) void csrABC_gemm1_kernel(
    const int* __restrict__ src, const int* __restrict__ dst,
    int* __restrict__ bucket_cnt, int* __restrict__ bucket_base,
    int* __restrict__ bucket_cursor, int* __restrict__ row_start,
    unsigned* __restrict__ tmp, int E, int NB, int nchunks,
    const float* __restrict__ h, const float* __restrict__ W1,
    const float* __restrict__ al1, const float* __restrict__ ar1,
    unsigned short* __restrict__ feat1b, float* __restrict__ el1,
    float* __restrict__ er1, int N) {
    __shared__ __align__(16) int smem[8192];  // 32 KB union (exact)
    const int tid = threadIdx.x;
    if ((int)blockIdx.x < nchunks) {
        // ---------------- partition body (uses 25.6 KB of the union) -------
        int* lh = smem;                               // 1024
        int* lex = smem + 1024;                       // 1024
        int* lcur = smem + 2048;                      // 1024 (scanner reuses)
        int* gbase_sh = smem + 3072;                  // 1024
        int* psum = smem + 4096;                      // 256
        unsigned* sortedv = (unsigned*)(smem + 4352); // 2048 -> ends 6400
        int* ticket_p = smem + 6400;                  // broadcast slot
        const int base_e = blockIdx.x * CH;
        const int cnt_e = min(CH, E - base_e);
        for (int i = tid; i < 1024; i += 256) lh[i] = 0;
        __syncthreads();
        // phase 1: histogram + stage packed edges in registers (<=8/thread)
        unsigned pk[8];
        int nmine = 0;
        for (int i = tid; i < cnt_e; i += 256) {
            int e = base_e + i;
            int d = dst[e];
            unsigned b = (unsigned)d >> 6;
            pk[nmine++] = (b << 22) | ((unsigned)(d & 63) << 16) | (unsigned)(src[e] & 0xFFFF);
            atomicAdd(&lh[b], 1);
        }
        __syncthreads();
        // publish local histogram to global counts
        for (int b = tid; b < NB; b += 256)
            if (lh[b]) atomicAdd(&bucket_cnt[b], lh[b]);
        __syncthreads();
        if (tid == 0) {
            __threadfence();
            *ticket_p = atomicAdd(&bucket_cnt[NB], 1);
        }
        __syncthreads();
        const int ticket = *ticket_p;
        __syncthreads();
        if (ticket == nchunks - 1) {
            // last finisher: global scan of bucket counts
            for (int i = tid; i < 1024; i += 256)
                lcur[i] = (i < NB) ? atomicAdd(&bucket_cnt[i], 0) : 0;
            __syncthreads();
            int c0s = lcur[tid * 4], c1s = lcur[tid * 4 + 1], c2s = lcur[tid * 4 + 2],
                c3s = lcur[tid * 4 + 3];
            int tot = c0s + c1s + c2s + c3s;
            psum[tid] = tot;
            __syncthreads();
            for (int off = 1; off < 256; off <<= 1) {
                int t = (tid >= off) ? psum[tid - off] : 0;
                __syncthreads();
                psum[tid] += t;
                __syncthreads();
            }
            int eb = psum[tid] - tot;
            int i0 = tid * 4;
            if (i0 < NB)     { bucket_base[i0]     = eb;               atomicExch(&bucket_cursor[i0], eb); }
            if (i0 + 1 < NB) { bucket_base[i0 + 1] = eb + c0s;         atomicExch(&bucket_cursor[i0 + 1], eb + c0s); }
            if (i0 + 2 < NB) { bucket_base[i0 + 2] = eb + c0s + c1s;   atomicExch(&bucket_cursor[i0 + 2], eb + c0s + c1s); }
            if (i0 + 3 < NB) { bucket_base[i0 + 3] = eb + c0s + c1s + c2s;
                               atomicExch(&bucket_cursor[i0 + 3], eb + c0s + c1s + c2s); }
            if (tid == 255) bucket_base[NB] = psum[255];  // == E
            if (tid == 0) row_start[N] = E;
            __syncthreads();
            if (tid == 0) {
                __threadfence();
                atomicExch(&bucket_cnt[NB + 1], 1);
            }
        }
        // local exclusive scan of lh (independent of global scan)
        int s0 = lh[tid * 4], s1 = lh[tid * 4 + 1], s2 = lh[tid * 4 + 2], s3 = lh[tid * 4 + 3];
        int tot = s0 + s1 + s2 + s3;
        psum[tid] = tot;
        __syncthreads();
        for (int off = 1; off < 256; off <<= 1) {
            int t = (tid >= off) ? psum[tid - off] : 0;
            __syncthreads();
            psum[tid] += t;
            __syncthreads();
        }
        int ebase = psum[tid] - tot;
        lex[tid * 4] = ebase;
        lex[tid * 4 + 1] = ebase + s0;
        lex[tid * 4 + 2] = ebase + s0 + s1;
        lex[tid * 4 + 3] = ebase + s0 + s1 + s2;
        __syncthreads();
        // wait for global scan (low-contention spin: s_sleep backoff)
        if (tid == 0) {
            while (atomicAdd(&bucket_cnt[NB + 1], 0) == 0) {
                __builtin_amdgcn_s_sleep(8);
            }
        }
        __syncthreads();
        // reserve contiguous global runs per bucket (device-scope RMW: coherent)
        for (int b = tid; b < NB; b += 256) {
            int c = lh[b];
            gbase_sh[b] = c ? atomicAdd(&bucket_cursor[b], c) : 0;
            lh[b] = 0;  // reuse as lcur
        }
        __syncthreads();
        // scatter from registers into LDS, sorted by bucket
        for (int j = 0; j < nmine; ++j) {
            unsigned v = pk[j];
            unsigned b = v >> 22;
            int r = atomicAdd(&lh[b], 1);
            sortedv[lex[b] + r] = v;
        }
        __syncthreads();
        for (int i = tid; i < cnt_e; i += 256) {
            unsigned v = sortedv[i];
            int b = v >> 22;
            tmp[gbase_sh[b] + (i - lex[b])] = v;
        }
    } else {
        // ---------------- gemm1 body (uses the full 32 KB as xs) ----------
        float* xs = (float*)smem;  // 64*128 floats = 32 KB
        const int row0 = ((int)blockIdx.x - nchunks) * 64;
        {
            const float4* s4 = (const float4*)h;
            float4* d4 = (float4*)xs;
            int base4 = row0 * 32;
            int tot4 = N * 32;
            for (int i = tid; i < 2048; i += 256)
                if (base4 + i < tot4) d4[i] = s4[base4 + i];
        }
        __syncthreads();
        const int lane = tid & 31;
        const int c0 = lane * 4;
        const int r0 = (tid >> 5) * 8;
        float acc[8][4] = {};
#pragma unroll 4
        for (int k = 0; k < 128; ++k) {
            float4 w = *(const float4*)(W1 + k * 128 + c0);
#pragma unroll
            for (int r = 0; r < 8; ++r) {
                float x = xs[(r0 + r) * 128 + k];
                acc[r][0] = fmaf(x, w.x, acc[r][0]);
                acc[r][1] = fmaf(x, w.y, acc[r][1]);
                acc[r][2] = fmaf(x, w.z, acc[r][2]);
                acc[r][3] = fmaf(x, w.w, acc[r][3]);
            }
        }
        float4 alv = *(const float4*)(al1 + c0);
        float4 arv = *(const float4*)(ar1 + c0);
#pragma unroll
        for (int r = 0; r < 8; ++r) {
            int row = row0 + r0 + r;
            if (row < N) {
                ushort4 fb;
                fb.x = f2bf(acc[r][0]);
                fb.y = f2bf(acc[r][1]);
                fb.z = f2bf(acc[r][2]);
                fb.w = f2bf(acc[r][3]);
                *(ushort4*)(feat1b + (size_t)row * 128 + c0) = fb;
                float pl = acc[r][0] * alv.x + acc[r][1] * alv.y + acc[r][2] * alv.z +
                           acc[r][3] * alv.w;
                float pr = acc[r][0] * arv.x + acc[r][1] * arv.y + acc[r][2] * arv.z +
                           acc[r][3] * arv.w;
#pragma unroll
                for (int off = 4; off >= 1; off >>= 1) {
                    pl += __shfl_xor(pl, off, 32);
                    pr += __shfl_xor(pr, off, 32);
                }
                if ((lane & 7) == 0) {
                    el1[row * 4 + (lane >> 3)] = pl;
                    er1[row * 4 + (lane >> 3)] = pr;
                }
            }
        }
    }
}

// ===========================================================================
// bucketD: per-bucket counting sort by dst low bits. 256 threads/block.
// ===========================================================================
__global__ __launch_bounds__(256) void bucketD_kernel(const unsigned* __restrict__ tmp,
                                                      const int* __restrict__ bucket_base,
                                                      int* __restrict__ srcs,
                                                      int* __restrict__ row_start,
                                                      int N, int NB) {
    __shared__ unsigned sval[DCAP];
    __shared__ int ssrc[DCAP];
    __shared__ int dh[64], dex[64], dcur[64];
    const int b = blockIdx.x;
    const int tid = threadIdx.x;  // 0..255
    const int gb = bucket_base[b], ge = bucket_base[b + 1];
    const int cnt = ge - gb;
    if (tid < 64) dh[tid] = 0;
    __syncthreads();
    if (cnt <= DCAP) {
        for (int i = tid; i < cnt; i += 256) {
            unsigned v = tmp[gb + i];
            sval[i] = v;
            atomicAdd(&dh[(v >> 16) & 63], 1);
        }
        __syncthreads();
        if (tid < 64) {
            int v = dh[tid], inc = v;
            for (int off = 1; off < 64; off <<= 1) {
                int t = __shfl_up(inc, off, 64);
                if (tid >= off) inc += t;
            }
            dex[tid] = inc - v;
            dcur[tid] = 0;
            int dglob = b * 64 + tid;
            if (dglob < N) row_start[dglob] = gb + inc - v;
        }
        __syncthreads();
        for (int i = tid; i < cnt; i += 256) {
            unsigned val = sval[i];
            int dl = (val >> 16) & 63;
            int r = atomicAdd(&dcur[dl], 1);
            ssrc[dex[dl] + r] = (int)(val & 0xFFFFu);
        }
        __syncthreads();
        for (int i = tid; i < cnt; i += 256) srcs[gb + i] = ssrc[i];
    } else {
        // robust fallback (never hit for this input)
        for (int i = tid; i < cnt; i += 256) atomicAdd(&dh[(tmp[gb + i] >> 16) & 63], 1);
        __syncthreads();
        if (tid < 64) {
            int v = dh[tid], inc = v;
            for (int off = 1; off < 64; off <<= 1) {
                int t = __shfl_up(inc, off, 64);
                if (tid >= off) inc += t;
            }
            dex[tid] = inc - v;
            dcur[tid] = 0;
            int dglob = b * 64 + tid;
            if (dglob < N) row_start[dglob] = gb + inc - v;
        }
        __syncthreads();
        for (int i = tid; i < cnt; i += 256) {
            unsigned val = tmp[gb + i];
            int dl = (val >> 16) & 63;
            int r = atomicAdd(&dcur[dl], 1);
            srcs[gb + dex[dl] + r] = (int)(val & 0xFFFFu);
        }
    }
}

// ===========================================================================
// GEMM2: feat2b(bf16) = out1b(relu'd bf16) @ W2; el2/er2 fused.
// 64 rows/block (32 KB LDS), 256 threads, 4x4 per thread.
// ===========================================================================
__global__ __launch_bounds__(256) void gemm2_fused(const unsigned short* __restrict__ out1b,
                                                   const float* __restrict__ W2,
                                                   const float* __restrict__ al2,
                                                   const float* __restrict__ ar2,
                                                   unsigned short* __restrict__ feat2b,
                                                   float* __restrict__ el2,
                                                   float* __restrict__ er2, int N) {
    __shared__ float xs[64 * 128];  // 32 KB
    const int tid = threadIdx.x;
    const int row0 = blockIdx.x * 64;
    {
        const uint4* s8 = (const uint4*)out1b;  // 8 bf16 per uint4
        int base8 = row0 * 16;
        int tot8 = N * 16;
        for (int i = tid; i < 1024; i += 256)
            if (base8 + i < tot8) {
                uint4 v = s8[base8 + i];
                float* o = xs + i * 8;
                o[0] = bf2f_lo(v.x);
                o[1] = bf2f_hi(v.x);
                o[2] = bf2f_lo(v.y);
                o[3] = bf2f_hi(v.y);
                o[4] = bf2f_lo(v.z);
                o[5] = bf2f_hi(v.z);
                o[6] = bf2f_lo(v.w);
                o[7] = bf2f_hi(v.w);
            }
    }
    __syncthreads();
    const int lane = tid & 15;
    const int c0 = lane * 4;
    const int r0 = (tid >> 4) * 4;  // 16 groups x 4 rows = 64
    float acc[4][4] = {};
#pragma unroll 4
    for (int k = 0; k < 128; ++k) {
        float4 w = *(const float4*)(W2 + k * 64 + c0);
#pragma unroll
        for (int r = 0; r < 4; ++r) {
            float x = xs[(r0 + r) * 128 + k];
            acc[r][0] = fmaf(x, w.x, acc[r][0]);
            acc[r][1] = fmaf(x, w.y, acc[r][1]);
            acc[r][2] = fmaf(x, w.z, acc[r][2]);
            acc[r][3] = fmaf(x, w.w, acc[r][3]);
        }
    }
    float4 alv = *(const float4*)(al2 + c0);
    float4 arv = *(const float4*)(ar2 + c0);
#pragma unroll
    for (int r = 0; r < 4; ++r) {
        int row = row0 + r0 + r;
        if (row < N) {
            ushort4 fb;
            fb.x = f2bf(acc[r][0]);
            fb.y = f2bf(acc[r][1]);
            fb.z = f2bf(acc[r][2]);
            fb.w = f2bf(acc[r][3]);
            *(ushort4*)(feat2b + (size_t)row * 64 + c0) = fb;
            float pl = acc[r][0] * alv.x + acc[r][1] * alv.y + acc[r][2] * alv.z +
                       acc[r][3] * alv.w;
            float pr = acc[r][0] * arv.x + acc[r][1] * arv.y + acc[r][2] * arv.z +
                       acc[r][3] * arv.w;
#pragma unroll
            for (int off = 8; off >= 1; off >>= 1) {
                pl += __shfl_xor(pl, off, 16);
                pr += __shfl_xor(pr, off, 16);
            }
            if (lane == 0) {
                el2[row] = pl;
                er2[row] = pr;
            }
        }
    }
}

// ===========================================================================
// Gather layer 1: one dst per wave, quarter-wave edge split (4 edges in
// flight), 16 lanes x 8 cols (16 B loads). Epilogue: +bias, ReLU, bf16 store.
// ===========================================================================
__global__ __launch_bounds__(256) void gather1_kernel(const int* __restrict__ row_start,
                                                      const int* __restrict__ srcs,
                                                      const float* __restrict__ el1,
                                                      const float* __restrict__ er1,
                                                      const unsigned short* __restrict__ feat1b,
                                                      const float* __restrict__ b1,
                                                      unsigned short* __restrict__ out1b,
                                                      int N) {
    __shared__ int s_sh[4][64];
    __shared__ float a_sh[4][256];
    const int tid = threadIdx.x;
    const int w = tid >> 6;       // wave in block
    const int lane = tid & 63;
    const int d = blockIdx.x * 4 + w;
    if (d >= N) return;
    const int beg = row_start[d], end = row_start[d + 1];
    const int q = lane >> 4;      // quarter: edges e ≡ q (mod 4)
    const int l16 = lane & 15;
    const int c0 = l16 * 8;       // 8 cols per lane
    const int h = l16 >> 2;       // head of this lane's columns
    float4 er4 = *(const float4*)(er1 + (size_t)d * 4);
    float acc[8] = {}, bcc[8] = {};
    float den = 0.f;
    for (int k0 = beg; k0 < end; k0 += 64) {
        const int M = min(64, end - k0);
        if (lane < M) {
            int s = srcs[k0 + lane];
            s_sh[w][lane] = s;
            float4 el4 = *(const float4*)(el1 + (size_t)s * 4);
            float v0 = el4.x + er4.x;
            float v1 = el4.y + er4.y;
            float v2 = el4.z + er4.z;
            float v3 = el4.w + er4.w;
            v0 = v0 > 0.f ? v0 : NEG_SLOPE * v0;
            v1 = v1 > 0.f ? v1 : NEG_SLOPE * v1;
            v2 = v2 > 0.f ? v2 : NEG_SLOPE * v2;
            v3 = v3 > 0.f ? v3 : NEG_SLOPE * v3;
            a_sh[w][lane * 4 + 0] = __expf(v0);
            a_sh[w][lane * 4 + 1] = __expf(v1);
            a_sh[w][lane * 4 + 2] = __expf(v2);
            a_sh[w][lane * 4 + 3] = __expf(v3);
        }
        wave_lds_fence();
        int e = q;
        for (; e + 4 < M; e += 8) {
            int s0 = s_sh[w][e], s1 = s_sh[w][e + 4];
            float a0 = a_sh[w][e * 4 + h];
            float a1 = a_sh[w][(e + 4) * 4 + h];
            uint4 f0 = *(const uint4*)(feat1b + (size_t)s0 * 128 + c0);
            uint4 f1 = *(const uint4*)(feat1b + (size_t)s1 * 128 + c0);
            den += a0 + a1;
            acc[0] = fmaf(bf2f_lo(f0.x), a0, acc[0]);
            acc[1] = fmaf(bf2f_hi(f0.x), a0, acc[1]);
            acc[2] = fmaf(bf2f_lo(f0.y), a0, acc[2]);
            acc[3] = fmaf(bf2f_hi(f0.y), a0, acc[3]);
            acc[4] = fmaf(bf2f_lo(f0.z), a0, acc[4]);
            acc[5] = fmaf(bf2f_hi(f0.z), a0, acc[5]);
            acc[6] = fmaf(bf2f_lo(f0.w), a0, acc[6]);
            acc[7] = fmaf(bf2f_hi(f0.w), a0, acc[7]);
            bcc[0] = fmaf(bf2f_lo(f1.x), a1, bcc[0]);
            bcc[1] = fmaf(bf2f_hi(f1.x), a1, bcc[1]);
            bcc[2] = fmaf(bf2f_lo(f1.y), a1, bcc[2]);
            bcc[3] = fmaf(bf2f_hi(f1.y), a1, bcc[3]);
            bcc[4] = fmaf(bf2f_lo(f1.z), a1, bcc[4]);
            bcc[5] = fmaf(bf2f_hi(f1.z), a1, bcc[5]);
            bcc[6] = fmaf(bf2f_lo(f1.w), a1, bcc[6]);
            bcc[7] = fmaf(bf2f_hi(f1.w), a1, bcc[7]);
        }
        while (e < M) {
            int s0 = s_sh[w][e];
            float a0 = a_sh[w][e * 4 + h];
            uint4 f0 = *(const uint4*)(feat1b + (size_t)s0 * 128 + c0);
            den += a0;
            acc[0] = fmaf(bf2f_lo(f0.x), a0, acc[0]);
            acc[1] = fmaf(bf2f_hi(f0.x), a0, acc[1]);
            acc[2] = fmaf(bf2f_lo(f0.y), a0, acc[2]);
            acc[3] = fmaf(bf2f_hi(f0.y), a0, acc[3]);
            acc[4] = fmaf(bf2f_lo(f0.z), a0, acc[4]);
            acc[5] = fmaf(bf2f_hi(f0.z), a0, acc[5]);
            acc[6] = fmaf(bf2f_lo(f0.w), a0, acc[6]);
            acc[7] = fmaf(bf2f_hi(f0.w), a0, acc[7]);
            e += 4;
        }
        wave_lds_fence();
    }
#pragma unroll
    for (int j = 0; j < 8; ++j) {
        acc[j] += bcc[j];
        acc[j] += __shfl_xor(acc[j], 16, 64);
        acc[j] += __shfl_xor(acc[j], 32, 64);
    }
    den += __shfl_xor(den, 16, 64);
    den += __shfl_xor(den, 32, 64);
    if (q == 0) {
        float inv = (end > beg) ? 1.f / den : 0.f;
        float4 bv0 = *(const float4*)(b1 + c0);
        float4 bv1 = *(const float4*)(b1 + c0 + 4);
        uint4 o;
        o.x = pack2bf(fmaxf(acc[0] * inv + bv0.x, 0.f), fmaxf(acc[1] * inv + bv0.y, 0.f));
        o.y = pack2bf(fmaxf(acc[2] * inv + bv0.z, 0.f), fmaxf(acc[3] * inv + bv0.w, 0.f));
        o.z = pack2bf(fmaxf(acc[4] * inv + bv1.x, 0.f), fmaxf(acc[5] * inv + bv1.y, 0.f));
        o.w = pack2bf(fmaxf(acc[6] * inv + bv1.z, 0.f), fmaxf(acc[7] * inv + bv1.w, 0.f));
        *(uint4*)(out1b + (size_t)d * 128 + c0) = o;
    }
}

// ===========================================================================
// Gather layer 2: octet split — 8 edges in flight, 8 lanes x 8 cols (16 B).
// ===========================================================================
__global__ __launch_bounds__(256) void gather2_kernel(const int* __restrict__ row_start,
                                                      const int* __restrict__ srcs,
                                                      const float* __restrict__ el2,
                                                      const float* __restrict__ er2,
                                                      const unsigned short* __restrict__ feat2b,
                                                      const float* __restrict__ b2,
                                                      float* __restrict__ out2, int N) {
    __shared__ int s_sh[4][64];
    __shared__ float a_sh[4][64];
    const int tid = threadIdx.x;
    const int w = tid >> 6;
    const int lane = tid & 63;
    const int d = blockIdx.x * 4 + w;
    if (d >= N) return;
    const int beg = row_start[d], end = row_start[d + 1];
    const int oct = lane >> 3;   // edges e ≡ oct (mod 8)
    const int l8 = lane & 7;
    const int c0 = l8 * 8;       // 8 cols per lane (8 lanes cover 64)
    const float er_d = er2[d];
    float acc[8] = {}, bcc[8] = {};
    float den = 0.f;
    for (int k0 = beg; k0 < end; k0 += 64) {
        const int M = min(64, end - k0);
        if (lane < M) {
            int s = srcs[k0 + lane];
            s_sh[w][lane] = s;
            float v = el2[s] + er_d;
            v = v > 0.f ? v : NEG_SLOPE * v;
            a_sh[w][lane] = __expf(v);
        }
        wave_lds_fence();
        int e = oct;
        for (; e + 8 < M; e += 16) {
            int s0 = s_sh[w][e], s1 = s_sh[w][e + 8];
            float a0 = a_sh[w][e], a1 = a_sh[w][e + 8];
            uint4 f0 = *(const uint4*)(feat2b + (size_t)s0 * 64 + c0);
            uint4 f1 = *(const uint4*)(feat2b + (size_t)s1 * 64 + c0);
            den += a0 + a1;
            acc[0] = fmaf(bf2f_lo(f0.x), a0, acc[0]);
            acc[1] = fmaf(bf2f_hi(f0.x), a0, acc[1]);
            acc[2] = fmaf(bf2f_lo(f0.y), a0, acc[2]);
            acc[3] = fmaf(bf2f_hi(f0.y), a0, acc[3]);
            acc[4] = fmaf(bf2f_lo(f0.z), a0, acc[4]);
            acc[5] = fmaf(bf2f_hi(f0.z), a0, acc[5]);
            acc[6] = fmaf(bf2f_lo(f0.w), a0, acc[6]);
            acc[7] = fmaf(bf2f_hi(f0.w), a0, acc[7]);
            bcc[0] = fmaf(bf2f_lo(f1.x), a1, bcc[0]);
            bcc[1] = fmaf(bf2f_hi(f1.x), a1, bcc[1]);
            bcc[2] = fmaf(bf2f_lo(f1.y), a1, bcc[2]);
            bcc[3] = fmaf(bf2f_hi(f1.y), a1, bcc[3]);
            bcc[4] = fmaf(bf2f_lo(f1.z), a1, bcc[4]);
            bcc[5] = fmaf(bf2f_hi(f1.z), a1, bcc[5]);
            bcc[6] = fmaf(bf2f_lo(f1.w), a1, bcc[6]);
            bcc[7] = fmaf(bf2f_hi(f1.w), a1, bcc[7]);
        }
        while (e < M) {
            int s0 = s_sh[w][e];
            float a0 = a_sh[w][e];
            uint4 f0 = *(const uint4*)(feat2b + (size_t)s0 * 64 + c0);
            den += a0;
            acc[0] = fmaf(bf2f_lo(f0.x), a0, acc[0]);
            acc[1] = fmaf(bf2f_hi(f0.x), a0, acc[1]);
            acc[2] = fmaf(bf2f_lo(f0.y), a0, acc[2]);
            acc[3] = fmaf(bf2f_hi(f0.y), a0, acc[3]);
            acc[4] = fmaf(bf2f_lo(f0.z), a0, acc[4]);
            acc[5] = fmaf(bf2f_hi(f0.z), a0, acc[5]);
            acc[6] = fmaf(bf2f_lo(f0.w), a0, acc[6]);
            acc[7] = fmaf(bf2f_hi(f0.w), a0, acc[7]);
            e += 8;
        }
        wave_lds_fence();
    }
#pragma unroll
    for (int j = 0; j < 8; ++j) {
        acc[j] += bcc[j];
        acc[j] += __shfl_xor(acc[j], 8, 64);
        acc[j] += __shfl_xor(acc[j], 16, 64);
        acc[j] += __shfl_xor(acc[j], 32, 64);
    }
    den += __shfl_xor(den, 8, 64);
    den += __shfl_xor(den, 16, 64);
    den += __shfl_xor(den, 32, 64);
    if (oct == 0) {
        float inv = (end > beg) ? 1.f / den : 0.f;
        float4 bv0 = *(const float4*)(b2 + c0);
        float4 bv1 = *(const float4*)(b2 + c0 + 4);
        *(float4*)(out2 + (size_t)d * 64 + c0) =
            make_float4(acc[0] * inv + bv0.x, acc[1] * inv + bv0.y,
                        acc[2] * inv + bv0.z, acc[3] * inv + bv0.w);
        *(float4*)(out2 + (size_t)d * 64 + c0 + 4) =
            make_float4(acc[4] * inv + bv1.x, acc[5] * inv + bv1.y,
                        acc[6] * inv + bv1.z, acc[7] * inv + bv1.w);
    }
}

// ===========================================================================
extern "C" void kernel_launch(void* const* d_in, const int* in_sizes, int n_in,
                              void* d_out, int out_size, void* d_ws, size_t ws_size,
                              hipStream_t stream) {
    const float* h   = (const float*)d_in[0];
    const int*   src = (const int*)d_in[1];
    const int*   dst = (const int*)d_in[2];
    const float* W1  = (const float*)d_in[3];
    const float* al1 = (const float*)d_in[4];
    const float* ar1 = (const float*)d_in[5];
    const float* b1  = (const float*)d_in[6];
    const float* W2  = (const float*)d_in[7];
    const float* al2 = (const float*)d_in[8];
    const float* ar2 = (const float*)d_in[9];
    const float* b2  = (const float*)d_in[10];

    const int N = in_sizes[0] / 128;  // 50000 (pack assumes N <= 65536)
    const int E = in_sizes[1];        // 800000
    const int NB = (N + 63) >> 6;     // 782 buckets

    char* ws = (char*)d_ws;
    size_t off = 0;
    auto alloc = [&](size_t elems) -> void* {  // elems are 4-byte units
        void* p = (void*)(ws + off);
        off += ((elems * 4 + 255) / 256) * 256;
        return p;
    };
    int* bucket_cnt    = (int*)alloc(NB + 2);  // [NB]=ticket, [NB+1]=scan-done
    int* bucket_base   = (int*)alloc(NB + 1);
    int* bucket_cursor = (int*)alloc(NB);
    unsigned* tmp      = (unsigned*)alloc(E);
    int* srcs          = (int*)alloc(E);
    int* row_start     = (int*)alloc(N + 1);
    float* el1   = (float*)alloc((size_t)N * 4);
    float* er1   = (float*)alloc((size_t)N * 4);
    unsigned short* feat1b = (unsigned short*)alloc((size_t)N * 64);  // N*128 bf16
    unsigned short* out1b  = (unsigned short*)alloc((size_t)N * 64);  // N*128 bf16 (relu'd)
    float* el2   = (float*)alloc(N);
    float* er2   = (float*)alloc(N);
    unsigned short* feat2b = (unsigned short*)alloc((size_t)N * 32);  // N*64 bf16
    float* out2  = (float*)d_out;

    const int nchunks = (E + CH - 1) / CH;
    const int gemm1_blocks = (N + 63) / 64;

    // --- CSR build (hist+scan+partition, last-finisher sync) + layer-1 GEMM ---
    hipMemsetAsync(bucket_cnt, 0, (size_t)(NB + 2) * 4, stream);
    csrABC_gemm1_kernel<<<nchunks + gemm1_blocks, 256, 0, stream>>>(
        src, dst, bucket_cnt, bucket_base, bucket_cursor, row_start, tmp, E, NB,
        nchunks, h, W1, al1, ar1, feat1b, el1, er1, N);
    bucketD_kernel<<<NB, 256, 0, stream>>>(tmp, bucket_base, srcs, row_start, N, NB);

    // --- layer 1 gather (writes relu'd bf16 layer-2 input) ---
    gather1_kernel<<<(N + 3) / 4, 256, 0, stream>>>(row_start, srcs, el1, er1, feat1b,
                                                    b1, out1b, N);

    // --- layer 2 ---
    gemm2_fused<<<(N + 63) / 64, 256, 0, stream>>>(out1b, W2, al2, ar2, feat2b, el2,
                                                   er2, N);
    gather2_kernel<<<(N + 3) / 4, 256, 0, stream>>>(row_start, srcs, el2, er2, feat2b,
                                                    b2, out2, N);
}

// Round 15
// 209.993 us; speedup vs baseline: 1.1294x; 1.1294x over previous
//
#include <hip/hip_runtime.h>

#define NEG_SLOPE 0.2f
#define CH 4096      // edges per partition block
#define DCAP 2048    // max edges per bucket handled via LDS fast path

__device__ inline unsigned short f2bf(float f) {
    unsigned u = __float_as_uint(f);
    unsigned r = (u + 0x7FFFu + ((u >> 16) & 1u)) >> 16;
    return (unsigned short)r;
}
__device__ inline unsigned pack2bf(float a, float b) {
    return (unsigned)f2bf(a) | ((unsigned)f2bf(b) << 16);
}
__device__ inline float bf2f(unsigned short s) {
    return __uint_as_float(((unsigned)s) << 16);
}
__device__ inline float bf2f_lo(unsigned u) { return __uint_as_float(u << 16); }
__device__ inline float bf2f_hi(unsigned u) { return __uint_as_float(u & 0xFFFF0000u); }
__device__ inline void wave_lds_fence() {
    asm volatile("s_waitcnt lgkmcnt(0)" ::: "memory");
}

// ===========================================================================
// FUSED: bucketAB (global histogram + scan, last-finisher) + bucketC (edge
// partition) || gemm1 (feat1b = h@W1 + el1/er1).
// Packed edge: (bucket<<22) | ((dst&63)<<16) | src   (requires N <= 65536)
// bucket_cnt layout: [0,NB) counts, [NB] ticket, [NB+1] scan-done flag.
// ===========================================================================
__global__ __launch_bounds__(256) void csrABC_gemm1_kernel(
    const int* __restrict__ src, const int* __restrict__ dst,
    int* __restrict__ bucket_cnt, int* __restrict__ bucket_base,
    int* __restrict__ bucket_cursor, int* __restrict__ row_start,
    unsigned* __restrict__ tmp, int E, int NB, int nchunks,
    const float* __restrict__ h, const float* __restrict__ W1,
    const float* __restrict__ al1, const float* __restrict__ ar1,
    unsigned short* __restrict__ feat1b, float* __restrict__ el1,
    float* __restrict__ er1, int N) {
    __shared__ __align__(16) int smem[8448];  // 33 KB union
    const int tid = threadIdx.x;
    if ((int)blockIdx.x < nchunks) {
        // ---------------- partition body ----------------
        int* lh = smem;                               // 1024
        int* lex = smem + 1024;                       // 1024
        int* lcur = smem + 2048;                      // 1024 (scanner reuses)
        int* gbase_sh = smem + 3072;                  // 1024
        int* psum = smem + 4096;                      // 256
        unsigned* sortedv = (unsigned*)(smem + 4352); // 4096
        const int base_e = blockIdx.x * CH;
        const int cnt_e = min(CH, E - base_e);
        for (int i = tid; i < 1024; i += 256) lh[i] = 0;
        __syncthreads();
        for (int i = tid; i < cnt_e; i += 256) atomicAdd(&lh[dst[base_e + i] >> 6], 1);
        __syncthreads();
        // publish local histogram to global counts
        for (int b = tid; b < NB; b += 256)
            if (lh[b]) atomicAdd(&bucket_cnt[b], lh[b]);
        __syncthreads();
        __shared__ int ticket_sh;
        if (tid == 0) {
            __threadfence();
            ticket_sh = atomicAdd(&bucket_cnt[NB], 1);
        }
        __syncthreads();
        if (ticket_sh == nchunks - 1) {
            // last finisher: global scan of bucket counts
            for (int i = tid; i < 1024; i += 256)
                lcur[i] = (i < NB) ? atomicAdd(&bucket_cnt[i], 0) : 0;
            __syncthreads();
            int c0s = lcur[tid * 4], c1s = lcur[tid * 4 + 1], c2s = lcur[tid * 4 + 2],
                c3s = lcur[tid * 4 + 3];
            int tot = c0s + c1s + c2s + c3s;
            psum[tid] = tot;
            __syncthreads();
            for (int off = 1; off < 256; off <<= 1) {
                int t = (tid >= off) ? psum[tid - off] : 0;
                __syncthreads();
                psum[tid] += t;
                __syncthreads();
            }
            int eb = psum[tid] - tot;
            int i0 = tid * 4;
            if (i0 < NB)     { bucket_base[i0]     = eb;               atomicExch(&bucket_cursor[i0], eb); }
            if (i0 + 1 < NB) { bucket_base[i0 + 1] = eb + c0s;         atomicExch(&bucket_cursor[i0 + 1], eb + c0s); }
            if (i0 + 2 < NB) { bucket_base[i0 + 2] = eb + c0s + c1s;   atomicExch(&bucket_cursor[i0 + 2], eb + c0s + c1s); }
            if (i0 + 3 < NB) { bucket_base[i0 + 3] = eb + c0s + c1s + c2s;
                               atomicExch(&bucket_cursor[i0 + 3], eb + c0s + c1s + c2s); }
            if (tid == 255) bucket_base[NB] = psum[255];  // == E
            if (tid == 0) row_start[N] = E;
            __syncthreads();
            if (tid == 0) {
                __threadfence();
                atomicExch(&bucket_cnt[NB + 1], 1);
            }
        }
        // local exclusive scan of lh (independent of global scan)
        int s0 = lh[tid * 4], s1 = lh[tid * 4 + 1], s2 = lh[tid * 4 + 2], s3 = lh[tid * 4 + 3];
        int tot = s0 + s1 + s2 + s3;
        psum[tid] = tot;
        __syncthreads();
        for (int off = 1; off < 256; off <<= 1) {
            int t = (tid >= off) ? psum[tid - off] : 0;
            __syncthreads();
            psum[tid] += t;
            __syncthreads();
        }
        int ebase = psum[tid] - tot;
        lex[tid * 4] = ebase;
        lex[tid * 4 + 1] = ebase + s0;
        lex[tid * 4 + 2] = ebase + s0 + s1;
        lex[tid * 4 + 3] = ebase + s0 + s1 + s2;
        __syncthreads();
        // wait for global scan (spin on device-scope flag)
        __shared__ int ready_sh;
        if (tid == 0) {
            while (atomicAdd(&bucket_cnt[NB + 1], 0) == 0) {}
            ready_sh = 1;
        }
        __syncthreads();
        (void)ready_sh;
        // reserve contiguous global runs per bucket (device-scope RMW: coherent)
        for (int b = tid; b < NB; b += 256) {
            int c = lh[b];
            gbase_sh[b] = c ? atomicAdd(&bucket_cursor[b], c) : 0;
            lh[b] = 0;  // reuse as lcur
        }
        __syncthreads();
        for (int i = tid; i < cnt_e; i += 256) {
            int e = base_e + i;
            int d = dst[e];
            unsigned b = (unsigned)d >> 6;
            int r = atomicAdd(&lh[b], 1);
            sortedv[lex[b] + r] =
                (b << 22) | ((unsigned)(d & 63) << 16) | (unsigned)(src[e] & 0xFFFF);
        }
        __syncthreads();
        for (int i = tid; i < cnt_e; i += 256) {
            unsigned v = sortedv[i];
            int b = v >> 22;
            tmp[gbase_sh[b] + (i - lex[b])] = v;
        }
    } else {
        // ---------------- gemm1 body ----------------
        float* xs = (float*)smem;  // 64*128 floats = 32 KB
        const int row0 = ((int)blockIdx.x - nchunks) * 64;
        {
            const float4* s4 = (const float4*)h;
            float4* d4 = (float4*)xs;
            int base4 = row0 * 32;
            int tot4 = N * 32;
            for (int i = tid; i < 2048; i += 256)
                if (base4 + i < tot4) d4[i] = s4[base4 + i];
        }
        __syncthreads();
        const int lane = tid & 31;
        const int c0 = lane * 4;
        const int r0 = (tid >> 5) * 8;
        float acc[8][4] = {};
#pragma unroll 4
        for (int k = 0; k < 128; ++k) {
            float4 w = *(const float4*)(W1 + k * 128 + c0);
#pragma unroll
            for (int r = 0; r < 8; ++r) {
                float x = xs[(r0 + r) * 128 + k];
                acc[r][0] = fmaf(x, w.x, acc[r][0]);
                acc[r][1] = fmaf(x, w.y, acc[r][1]);
                acc[r][2] = fmaf(x, w.z, acc[r][2]);
                acc[r][3] = fmaf(x, w.w, acc[r][3]);
            }
        }
        float4 alv = *(const float4*)(al1 + c0);
        float4 arv = *(const float4*)(ar1 + c0);
#pragma unroll
        for (int r = 0; r < 8; ++r) {
            int row = row0 + r0 + r;
            if (row < N) {
                ushort4 fb;
                fb.x = f2bf(acc[r][0]);
                fb.y = f2bf(acc[r][1]);
                fb.z = f2bf(acc[r][2]);
                fb.w = f2bf(acc[r][3]);
                *(ushort4*)(feat1b + (size_t)row * 128 + c0) = fb;
                float pl = acc[r][0] * alv.x + acc[r][1] * alv.y + acc[r][2] * alv.z +
                           acc[r][3] * alv.w;
                float pr = acc[r][0] * arv.x + acc[r][1] * arv.y + acc[r][2] * arv.z +
                           acc[r][3] * arv.w;
#pragma unroll
                for (int off = 4; off >= 1; off >>= 1) {
                    pl += __shfl_xor(pl, off, 32);
                    pr += __shfl_xor(pr, off, 32);
                }
                if ((lane & 7) == 0) {
                    el1[row * 4 + (lane >> 3)] = pl;
                    er1[row * 4 + (lane >> 3)] = pr;
                }
            }
        }
    }
}

// ===========================================================================
// bucketD: per-bucket counting sort by dst low bits. 256 threads/block.
// ===========================================================================
__global__ __launch_bounds__(256) void bucketD_kernel(const unsigned* __restrict__ tmp,
                                                      const int* __restrict__ bucket_base,
                                                      int* __restrict__ srcs,
                                                      int* __restrict__ row_start,
                                                      int N, int NB) {
    __shared__ unsigned sval[DCAP];
    __shared__ int ssrc[DCAP];
    __shared__ int dh[64], dex[64], dcur[64];
    const int b = blockIdx.x;
    const int tid = threadIdx.x;  // 0..255
    const int gb = bucket_base[b], ge = bucket_base[b + 1];
    const int cnt = ge - gb;
    if (tid < 64) dh[tid] = 0;
    __syncthreads();
    if (cnt <= DCAP) {
        for (int i = tid; i < cnt; i += 256) {
            unsigned v = tmp[gb + i];
            sval[i] = v;
            atomicAdd(&dh[(v >> 16) & 63], 1);
        }
        __syncthreads();
        if (tid < 64) {
            int v = dh[tid], inc = v;
            for (int off = 1; off < 64; off <<= 1) {
                int t = __shfl_up(inc, off, 64);
                if (tid >= off) inc += t;
            }
            dex[tid] = inc - v;
            dcur[tid] = 0;
            int dglob = b * 64 + tid;
            if (dglob < N) row_start[dglob] = gb + inc - v;
        }
        __syncthreads();
        for (int i = tid; i < cnt; i += 256) {
            unsigned val = sval[i];
            int dl = (val >> 16) & 63;
            int r = atomicAdd(&dcur[dl], 1);
            ssrc[dex[dl] + r] = (int)(val & 0xFFFFu);
        }
        __syncthreads();
        for (int i = tid; i < cnt; i += 256) srcs[gb + i] = ssrc[i];
    } else {
        // robust fallback (never hit for this input)
        for (int i = tid; i < cnt; i += 256) atomicAdd(&dh[(tmp[gb + i] >> 16) & 63], 1);
        __syncthreads();
        if (tid < 64) {
            int v = dh[tid], inc = v;
            for (int off = 1; off < 64; off <<= 1) {
                int t = __shfl_up(inc, off, 64);
                if (tid >= off) inc += t;
            }
            dex[tid] = inc - v;
            dcur[tid] = 0;
            int dglob = b * 64 + tid;
            if (dglob < N) row_start[dglob] = gb + inc - v;
        }
        __syncthreads();
        for (int i = tid; i < cnt; i += 256) {
            unsigned val = tmp[gb + i];
            int dl = (val >> 16) & 63;
            int r = atomicAdd(&dcur[dl], 1);
            srcs[gb + dex[dl] + r] = (int)(val & 0xFFFFu);
        }
    }
}

// ===========================================================================
// GEMM2: feat2b(bf16) = out1b(relu'd bf16) @ W2; el2/er2 fused.
// 64 rows/block (32 KB LDS), 256 threads, 4x4 per thread.
// ===========================================================================
__global__ __launch_bounds__(256) void gemm2_fused(const unsigned short* __restrict__ out1b,
                                                   const float* __restrict__ W2,
                                                   const float* __restrict__ al2,
                                                   const float* __restrict__ ar2,
                                                   unsigned short* __restrict__ feat2b,
                                                   float* __restrict__ el2,
                                                   float* __restrict__ er2, int N) {
    __shared__ float xs[64 * 128];  // 32 KB
    const int tid = threadIdx.x;
    const int row0 = blockIdx.x * 64;
    {
        const uint4* s8 = (const uint4*)out1b;  // 8 bf16 per uint4
        int base8 = row0 * 16;
        int tot8 = N * 16;
        for (int i = tid; i < 1024; i += 256)
            if (base8 + i < tot8) {
                uint4 v = s8[base8 + i];
                float* o = xs + i * 8;
                o[0] = bf2f_lo(v.x);
                o[1] = bf2f_hi(v.x);
                o[2] = bf2f_lo(v.y);
                o[3] = bf2f_hi(v.y);
                o[4] = bf2f_lo(v.z);
                o[5] = bf2f_hi(v.z);
                o[6] = bf2f_lo(v.w);
                o[7] = bf2f_hi(v.w);
            }
    }
    __syncthreads();
    const int lane = tid & 15;
    const int c0 = lane * 4;
    const int r0 = (tid >> 4) * 4;  // 16 groups x 4 rows = 64
    float acc[4][4] = {};
#pragma unroll 4
    for (int k = 0; k < 128; ++k) {
        float4 w = *(const float4*)(W2 + k * 64 + c0);
#pragma unroll
        for (int r = 0; r < 4; ++r) {
            float x = xs[(r0 + r) * 128 + k];
            acc[r][0] = fmaf(x, w.x, acc[r][0]);
            acc[r][1] = fmaf(x, w.y, acc[r][1]);
            acc[r][2] = fmaf(x, w.z, acc[r][2]);
            acc[r][3] = fmaf(x, w.w, acc[r][3]);
        }
    }
    float4 alv = *(const float4*)(al2 + c0);
    float4 arv = *(const float4*)(ar2 + c0);
#pragma unroll
    for (int r = 0; r < 4; ++r) {
        int row = row0 + r0 + r;
        if (row < N) {
            ushort4 fb;
            fb.x = f2bf(acc[r][0]);
            fb.y = f2bf(acc[r][1]);
            fb.z = f2bf(acc[r][2]);
            fb.w = f2bf(acc[r][3]);
            *(ushort4*)(feat2b + (size_t)row * 64 + c0) = fb;
            float pl = acc[r][0] * alv.x + acc[r][1] * alv.y + acc[r][2] * alv.z +
                       acc[r][3] * alv.w;
            float pr = acc[r][0] * arv.x + acc[r][1] * arv.y + acc[r][2] * arv.z +
                       acc[r][3] * arv.w;
#pragma unroll
            for (int off = 8; off >= 1; off >>= 1) {
                pl += __shfl_xor(pl, off, 16);
                pr += __shfl_xor(pr, off, 16);
            }
            if (lane == 0) {
                el2[row] = pl;
                er2[row] = pr;
            }
        }
    }
}

// ===========================================================================
// Gather layer 1: one dst per wave, quarter-wave edge split (4 edges in
// flight), 16 lanes x 8 cols (16 B loads). Epilogue: +bias, ReLU, bf16 store.
// ===========================================================================
__global__ __launch_bounds__(256) void gather1_kernel(const int* __restrict__ row_start,
                                                      const int* __restrict__ srcs,
                                                      const float* __restrict__ el1,
                                                      const float* __restrict__ er1,
                                                      const unsigned short* __restrict__ feat1b,
                                                      const float* __restrict__ b1,
                                                      unsigned short* __restrict__ out1b,
                                                      int N) {
    __shared__ int s_sh[4][64];
    __shared__ float a_sh[4][256];
    const int tid = threadIdx.x;
    const int w = tid >> 6;       // wave in block
    const int lane = tid & 63;
    const int d = blockIdx.x * 4 + w;
    if (d >= N) return;
    const int beg = row_start[d], end = row_start[d + 1];
    const int q = lane >> 4;      // quarter: edges e ≡ q (mod 4)
    const int l16 = lane & 15;
    const int c0 = l16 * 8;       // 8 cols per lane
    const int h = l16 >> 2;       // head of this lane's columns
    float4 er4 = *(const float4*)(er1 + (size_t)d * 4);
    float acc[8] = {}, bcc[8] = {};
    float den = 0.f;
    for (int k0 = beg; k0 < end; k0 += 64) {
        const int M = min(64, end - k0);
        if (lane < M) {
            int s = srcs[k0 + lane];
            s_sh[w][lane] = s;
            float4 el4 = *(const float4*)(el1 + (size_t)s * 4);
            float v0 = el4.x + er4.x;
            float v1 = el4.y + er4.y;
            float v2 = el4.z + er4.z;
            float v3 = el4.w + er4.w;
            v0 = v0 > 0.f ? v0 : NEG_SLOPE * v0;
            v1 = v1 > 0.f ? v1 : NEG_SLOPE * v1;
            v2 = v2 > 0.f ? v2 : NEG_SLOPE * v2;
            v3 = v3 > 0.f ? v3 : NEG_SLOPE * v3;
            a_sh[w][lane * 4 + 0] = __expf(v0);
            a_sh[w][lane * 4 + 1] = __expf(v1);
            a_sh[w][lane * 4 + 2] = __expf(v2);
            a_sh[w][lane * 4 + 3] = __expf(v3);
        }
        wave_lds_fence();
        int e = q;
        for (; e + 4 < M; e += 8) {
            int s0 = s_sh[w][e], s1 = s_sh[w][e + 4];
            float a0 = a_sh[w][e * 4 + h];
            float a1 = a_sh[w][(e + 4) * 4 + h];
            uint4 f0 = *(const uint4*)(feat1b + (size_t)s0 * 128 + c0);
            uint4 f1 = *(const uint4*)(feat1b + (size_t)s1 * 128 + c0);
            den += a0 + a1;
            acc[0] = fmaf(bf2f_lo(f0.x), a0, acc[0]);
            acc[1] = fmaf(bf2f_hi(f0.x), a0, acc[1]);
            acc[2] = fmaf(bf2f_lo(f0.y), a0, acc[2]);
            acc[3] = fmaf(bf2f_hi(f0.y), a0, acc[3]);
            acc[4] = fmaf(bf2f_lo(f0.z), a0, acc[4]);
            acc[5] = fmaf(bf2f_hi(f0.z), a0, acc[5]);
            acc[6] = fmaf(bf2f_lo(f0.w), a0, acc[6]);
            acc[7] = fmaf(bf2f_hi(f0.w), a0, acc[7]);
            bcc[0] = fmaf(bf2f_lo(f1.x), a1, bcc[0]);
            bcc[1] = fmaf(bf2f_hi(f1.x), a1, bcc[1]);
            bcc[2] = fmaf(bf2f_lo(f1.y), a1, bcc[2]);
            bcc[3] = fmaf(bf2f_hi(f1.y), a1, bcc[3]);
            bcc[4] = fmaf(bf2f_lo(f1.z), a1, bcc[4]);
            bcc[5] = fmaf(bf2f_hi(f1.z), a1, bcc[5]);
            bcc[6] = fmaf(bf2f_lo(f1.w), a1, bcc[6]);
            bcc[7] = fmaf(bf2f_hi(f1.w), a1, bcc[7]);
        }
        while (e < M) {
            int s0 = s_sh[w][e];
            float a0 = a_sh[w][e * 4 + h];
            uint4 f0 = *(const uint4*)(feat1b + (size_t)s0 * 128 + c0);
            den += a0;
            acc[0] = fmaf(bf2f_lo(f0.x), a0, acc[0]);
            acc[1] = fmaf(bf2f_hi(f0.x), a0, acc[1]);
            acc[2] = fmaf(bf2f_lo(f0.y), a0, acc[2]);
            acc[3] = fmaf(bf2f_hi(f0.y), a0, acc[3]);
            acc[4] = fmaf(bf2f_lo(f0.z), a0, acc[4]);
            acc[5] = fmaf(bf2f_hi(f0.z), a0, acc[5]);
            acc[6] = fmaf(bf2f_lo(f0.w), a0, acc[6]);
            acc[7] = fmaf(bf2f_hi(f0.w), a0, acc[7]);
            e += 4;
        }
        wave_lds_fence();
    }
#pragma unroll
    for (int j = 0; j < 8; ++j) {
        acc[j] += bcc[j];
        acc[j] += __shfl_xor(acc[j], 16, 64);
        acc[j] += __shfl_xor(acc[j], 32, 64);
    }
    den += __shfl_xor(den, 16, 64);
    den += __shfl_xor(den, 32, 64);
    if (q == 0) {
        float inv = (end > beg) ? 1.f / den : 0.f;
        float4 bv0 = *(const float4*)(b1 + c0);
        float4 bv1 = *(const float4*)(b1 + c0 + 4);
        uint4 o;
        o.x = pack2bf(fmaxf(acc[0] * inv + bv0.x, 0.f), fmaxf(acc[1] * inv + bv0.y, 0.f));
        o.y = pack2bf(fmaxf(acc[2] * inv + bv0.z, 0.f), fmaxf(acc[3] * inv + bv0.w, 0.f));
        o.z = pack2bf(fmaxf(acc[4] * inv + bv1.x, 0.f), fmaxf(acc[5] * inv + bv1.y, 0.f));
        o.w = pack2bf(fmaxf(acc[6] * inv + bv1.z, 0.f), fmaxf(acc[7] * inv + bv1.w, 0.f));
        *(uint4*)(out1b + (size_t)d * 128 + c0) = o;
    }
}

// ===========================================================================
// Gather layer 2: octet split — 8 edges in flight, 8 lanes x 8 cols (16 B).
// ===========================================================================
__global__ __launch_bounds__(256) void gather2_kernel(const int* __restrict__ row_start,
                                                      const int* __restrict__ srcs,
                                                      const float* __restrict__ el2,
                                                      const float* __restrict__ er2,
                                                      const unsigned short* __restrict__ feat2b,
                                                      const float* __restrict__ b2,
                                                      float* __restrict__ out2, int N) {
    __shared__ int s_sh[4][64];
    __shared__ float a_sh[4][64];
    const int tid = threadIdx.x;
    const int w = tid >> 6;
    const int lane = tid & 63;
    const int d = blockIdx.x * 4 + w;
    if (d >= N) return;
    const int beg = row_start[d], end = row_start[d + 1];
    const int oct = lane >> 3;   // edges e ≡ oct (mod 8)
    const int l8 = lane & 7;
    const int c0 = l8 * 8;       // 8 cols per lane (8 lanes cover 64)
    const float er_d = er2[d];
    float acc[8] = {}, bcc[8] = {};
    float den = 0.f;
    for (int k0 = beg; k0 < end; k0 += 64) {
        const int M = min(64, end - k0);
        if (lane < M) {
            int s = srcs[k0 + lane];
            s_sh[w][lane] = s;
            float v = el2[s] + er_d;
            v = v > 0.f ? v : NEG_SLOPE * v;
            a_sh[w][lane] = __expf(v);
        }
        wave_lds_fence();
        int e = oct;
        for (; e + 8 < M; e += 16) {
            int s0 = s_sh[w][e], s1 = s_sh[w][e + 8];
            float a0 = a_sh[w][e], a1 = a_sh[w][e + 8];
            uint4 f0 = *(const uint4*)(feat2b + (size_t)s0 * 64 + c0);
            uint4 f1 = *(const uint4*)(feat2b + (size_t)s1 * 64 + c0);
            den += a0 + a1;
            acc[0] = fmaf(bf2f_lo(f0.x), a0, acc[0]);
            acc[1] = fmaf(bf2f_hi(f0.x), a0, acc[1]);
            acc[2] = fmaf(bf2f_lo(f0.y), a0, acc[2]);
            acc[3] = fmaf(bf2f_hi(f0.y), a0, acc[3]);
            acc[4] = fmaf(bf2f_lo(f0.z), a0, acc[4]);
            acc[5] = fmaf(bf2f_hi(f0.z), a0, acc[5]);
            acc[6] = fmaf(bf2f_lo(f0.w), a0, acc[6]);
            acc[7] = fmaf(bf2f_hi(f0.w), a0, acc[7]);
            bcc[0] = fmaf(bf2f_lo(f1.x), a1, bcc[0]);
            bcc[1] = fmaf(bf2f_hi(f1.x), a1, bcc[1]);
            bcc[2] = fmaf(bf2f_lo(f1.y), a1, bcc[2]);
            bcc[3] = fmaf(bf2f_hi(f1.y), a1, bcc[3]);
            bcc[4] = fmaf(bf2f_lo(f1.z), a1, bcc[4]);
            bcc[5] = fmaf(bf2f_hi(f1.z), a1, bcc[5]);
            bcc[6] = fmaf(bf2f_lo(f1.w), a1, bcc[6]);
            bcc[7] = fmaf(bf2f_hi(f1.w), a1, bcc[7]);
        }
        while (e < M) {
            int s0 = s_sh[w][e];
            float a0 = a_sh[w][e];
            uint4 f0 = *(const uint4*)(feat2b + (size_t)s0 * 64 + c0);
            den += a0;
            acc[0] = fmaf(bf2f_lo(f0.x), a0, acc[0]);
            acc[1] = fmaf(bf2f_hi(f0.x), a0, acc[1]);
            acc[2] = fmaf(bf2f_lo(f0.y), a0, acc[2]);
            acc[3] = fmaf(bf2f_hi(f0.y), a0, acc[3]);
            acc[4] = fmaf(bf2f_lo(f0.z), a0, acc[4]);
            acc[5] = fmaf(bf2f_hi(f0.z), a0, acc[5]);
            acc[6] = fmaf(bf2f_lo(f0.w), a0, acc[6]);
            acc[7] = fmaf(bf2f_hi(f0.w), a0, acc[7]);
            e += 8;
        }
        wave_lds_fence();
    }
#pragma unroll
    for (int j = 0; j < 8; ++j) {
        acc[j] += bcc[j];
        acc[j] += __shfl_xor(acc[j], 8, 64);
        acc[j] += __shfl_xor(acc[j], 16, 64);
        acc[j] += __shfl_xor(acc[j], 32, 64);
    }
    den += __shfl_xor(den, 8, 64);
    den += __shfl_xor(den, 16, 64);
    den += __shfl_xor(den, 32, 64);
    if (oct == 0) {
        float inv = (end > beg) ? 1.f / den : 0.f;
        float4 bv0 = *(const float4*)(b2 + c0);
        float4 bv1 = *(const float4*)(b2 + c0 + 4);
        *(float4*)(out2 + (size_t)d * 64 + c0) =
            make_float4(acc[0] * inv + bv0.x, acc[1] * inv + bv0.y,
                        acc[2] * inv + bv0.z, acc[3] * inv + bv0.w);
        *(float4*)(out2 + (size_t)d * 64 + c0 + 4) =
            make_float4(acc[4] * inv + bv1.x, acc[5] * inv + bv1.y,
                        acc[6] * inv + bv1.z, acc[7] * inv + bv1.w);
    }
}

// ===========================================================================
extern "C" void kernel_launch(void* const* d_in, const int* in_sizes, int n_in,
                              void* d_out, int out_size, void* d_ws, size_t ws_size,
                              hipStream_t stream) {
    const float* h   = (const float*)d_in[0];
    const int*   src = (const int*)d_in[1];
    const int*   dst = (const int*)d_in[2];
    const float* W1  = (const float*)d_in[3];
    const float* al1 = (const float*)d_in[4];
    const float* ar1 = (const float*)d_in[5];
    const float* b1  = (const float*)d_in[6];
    const float* W2  = (const float*)d_in[7];
    const float* al2 = (const float*)d_in[8];
    const float* ar2 = (const float*)d_in[9];
    const float* b2  = (const float*)d_in[10];

    const int N = in_sizes[0] / 128;  // 50000 (pack assumes N <= 65536)
    const int E = in_sizes[1];        // 800000
    const int NB = (N + 63) >> 6;     // 782 buckets

    char* ws = (char*)d_ws;
    size_t off = 0;
    auto alloc = [&](size_t elems) -> void* {  // elems are 4-byte units
        void* p = (void*)(ws + off);
        off += ((elems * 4 + 255) / 256) * 256;
        return p;
    };
    int* bucket_cnt    = (int*)alloc(NB + 2);  // [NB]=ticket, [NB+1]=scan-done
    int* bucket_base   = (int*)alloc(NB + 1);
    int* bucket_cursor = (int*)alloc(NB);
    unsigned* tmp      = (unsigned*)alloc(E);
    int* srcs          = (int*)alloc(E);
    int* row_start     = (int*)alloc(N + 1);
    float* el1   = (float*)alloc((size_t)N * 4);
    float* er1   = (float*)alloc((size_t)N * 4);
    unsigned short* feat1b = (unsigned short*)alloc((size_t)N * 64);  // N*128 bf16
    unsigned short* out1b  = (unsigned short*)alloc((size_t)N * 64);  // N*128 bf16 (relu'd)
    float* el2   = (float*)alloc(N);
    float* er2   = (float*)alloc(N);
    unsigned short* feat2b = (unsigned short*)alloc((size_t)N * 32);  // N*64 bf16
    float* out2  = (float*)d_out;

    const int nchunks = (E + CH - 1) / CH;
    const int gemm1_blocks = (N + 63) / 64;

    // --- CSR build (hist+scan+partition, last-finisher sync) + layer-1 GEMM ---
    hipMemsetAsync(bucket_cnt, 0, (size_t)(NB + 2) * 4, stream);
    csrABC_gemm1_kernel<<<nchunks + gemm1_blocks, 256, 0, stream>>>(
        src, dst, bucket_cnt, bucket_base, bucket_cursor, row_start, tmp, E, NB,
        nchunks, h, W1, al1, ar1, feat1b, el1, er1, N);
    bucketD_kernel<<<NB, 256, 0, stream>>>(tmp, bucket_base, srcs, row_start, N, NB);

    // --- layer 1 gather (writes relu'd bf16 layer-2 input) ---
    gather1_kernel<<<(N + 3) / 4, 256, 0, stream>>>(row_start, srcs, el1, er1, feat1b,
                                                    b1, out1b, N);

    // --- layer 2 ---
    gemm2_fused<<<(N + 63) / 64, 256, 0, stream>>>(out1b, W2, al2, ar2, feat2b, el2,
                                                   er2, N);
    gather2_kernel<<<(N + 3) / 4, 256, 0, stream>>>(row_start, srcs, el2, er2, feat2b,
                                                    b2, out2, N);
}